// Round 7
// baseline (93.563 us; speedup 1.0000x reference)
//
#include <hip/hip_runtime.h>
#include <math.h>

#define N_ 2048
#define K_ 512
#define J_ 256
#define KS 16              // k-splits
#define KSL (K_ / KS)      // 32 k per split
#define NB 16              // n-rows per block

typedef __attribute__((ext_vector_type(2))) float v2f;

// lane <-> j decomposition. Thread t owns column j=t and a 32-k slice of w in
// REGISTERS (8 float4, one-time load). x[n][kslice] is wave-uniform -> uniform
// loads, each x element read once device-wide. Inner loop: pure VALU
// (pk_mul + max3/min3) + 2 coalesced stores. NO LDS, NO SMEM streaming.
// Grid (128 nb, 16 ks) = 2048 blocks; siblings share id%8 -> same XCD partials.
__global__ __launch_bounds__(256, 4) void mam_partial(
    const float* __restrict__ x, const float* __restrict__ w,
    float* __restrict__ pmax, float* __restrict__ pmin)
{
    const int t  = threadIdx.x;          // j = t
    const int nb = blockIdx.x;
    const int ks = blockIdx.y;
    const int n0 = nb * NB;
    const int kc = ks * KSL;

    // one-time w preload: w[t][kc..kc+31] -> 8 float4 in VGPRs (32 KB/block, line-exact)
    float4 wr[8];
    const float4* wp = (const float4*)(w + (size_t)t * K_ + kc);
#pragma unroll
    for (int q = 0; q < 8; ++q) wr[q] = wp[q];

    const float* xp = x + (size_t)n0 * K_ + kc;   // wave-uniform base

    float4 xa[8], xb[8];
#pragma unroll
    for (int q = 0; q < 8; ++q) xa[q] = ((const float4*)xp)[q];   // n0 row

#define REDUCE_STORE(BUF, NIDX)                                            \
    {                                                                      \
        float mx = -__builtin_inff(), mn = __builtin_inff();               \
        _Pragma("unroll")                                                  \
        for (int q = 0; q < 8; ++q) {                                      \
            const v2f pa = (v2f){BUF[q].x, BUF[q].y} *                     \
                           (v2f){wr[q].x, wr[q].y};                        \
            const v2f pb = (v2f){BUF[q].z, BUF[q].w} *                     \
                           (v2f){wr[q].z, wr[q].w};                        \
            mx = fmaxf(fmaxf(mx, pa.x), pa.y);                             \
            mn = fminf(fminf(mn, pa.x), pa.y);                             \
            mx = fmaxf(fmaxf(mx, pb.x), pb.y);                             \
            mn = fminf(fminf(mn, pb.x), pb.y);                             \
        }                                                                  \
        const size_t off = ((size_t)ks * N_ + n0 + (NIDX)) * J_ + t;       \
        pmax[off] = mx;                                                    \
        pmin[off] = mn;                                                    \
    }

    for (int n = 0; n < NB; n += 2) {
        // prefetch row n+1 into xb, then reduce row n from xa
        const float* p1 = xp + (size_t)(n + 1) * K_;
#pragma unroll
        for (int q = 0; q < 8; ++q) xb[q] = ((const float4*)p1)[q];
        REDUCE_STORE(xa, n)
        // prefetch row n+2 into xa, then reduce row n+1 from xb
        if (n + 2 < NB) {
            const float* p2 = xp + (size_t)(n + 2) * K_;
#pragma unroll
            for (int q = 0; q < 8; ++q) xa[q] = ((const float4*)p2)[q];
        }
        REDUCE_STORE(xb, n + 1)
    }
#undef REDUCE_STORE
}

// Fold 16 K-splits + bias. 512 blocks; block b handles n-tile b&127 (same id%8
// as the partial writers -> same-XCD L2 reads). One float4 out per thread.
__global__ __launch_bounds__(256) void mam_combine(
    const float* __restrict__ pmax, const float* __restrict__ pmin,
    const float* __restrict__ bias, float* __restrict__ out)
{
    const int b   = blockIdx.x;
    const int nb  = b & 127;
    const int sub = b >> 7;                        // 0..3
    const int n   = nb * NB + sub * 4 + (threadIdx.x >> 6);
    const int c4  = threadIdx.x & 63;              // float4 column
    const int f   = n * (J_ / 4) + c4;
    const int PLANE4 = N_ * J_ / 4;

    const float4* pm = (const float4*)pmax;
    const float4* pn = (const float4*)pmin;
    float4 a = pm[f];
    float4 c = pn[f];
#pragma unroll
    for (int s = 1; s < KS; ++s) {
        const float4 a2 = pm[(size_t)s * PLANE4 + f];
        const float4 c2 = pn[(size_t)s * PLANE4 + f];
        a.x = fmaxf(a.x, a2.x); a.y = fmaxf(a.y, a2.y);
        a.z = fmaxf(a.z, a2.z); a.w = fmaxf(a.w, a2.w);
        c.x = fminf(c.x, c2.x); c.y = fminf(c.y, c2.y);
        c.z = fminf(c.z, c2.z); c.w = fminf(c.w, c2.w);
    }
    const float4 bi = ((const float4*)bias)[c4];
    float4 o;
    o.x = a.x + c.x + bi.x;
    o.y = a.y + c.y + bi.y;
    o.z = a.z + c.z + bi.z;
    o.w = a.w + c.w + bi.w;
    ((float4*)out)[f] = o;
}

// Fallback if ws is too small (not expected; ws ~256 MB).
__global__ __launch_bounds__(256) void mam_naive(
    const float* __restrict__ x, const float* __restrict__ w,
    const float* __restrict__ bias, float* __restrict__ out)
{
    const int n = blockIdx.x;
    const int j = threadIdx.x;
    float mx = -__builtin_inff(), mn = __builtin_inff();
    for (int k = 0; k < K_; ++k) {
        const float p = x[(size_t)n * K_ + k] * w[(size_t)j * K_ + k];
        mx = fmaxf(mx, p);
        mn = fminf(mn, p);
    }
    out[(size_t)n * J_ + j] = mx + mn + bias[j];
}

extern "C" void kernel_launch(void* const* d_in, const int* in_sizes, int n_in,
                              void* d_out, int out_size, void* d_ws, size_t ws_size,
                              hipStream_t stream) {
    const float* x    = (const float*)d_in[0];
    const float* w    = (const float*)d_in[1];
    const float* bias = (const float*)d_in[2];
    float* out = (float*)d_out;

    const size_t need = (size_t)KS * 2 * N_ * J_ * sizeof(float);  // 64 MB
    if (ws_size >= need) {
        float* pmax = (float*)d_ws;
        float* pmin = pmax + (size_t)KS * N_ * J_;
        mam_partial<<<dim3(N_ / NB, KS), 256, 0, stream>>>(x, w, pmax, pmin);
        mam_combine<<<dim3(512), 256, 0, stream>>>(pmax, pmin, bias, out);
    } else {
        mam_naive<<<N_, 256, 0, stream>>>(x, w, bias, out);
    }
}